// Round 9
// baseline (1326.316 us; speedup 1.0000x reference)
//
#include <hip/hip_runtime.h>
#include <hip/hip_bf16.h>
#include <stdint.h>

typedef __attribute__((ext_vector_type(8))) short short8;
typedef __attribute__((ext_vector_type(16))) float f32x16;

#define CD 256   // channels
#define HD 512   // hidden
#define GATE_GRID 512

// ---------- helpers ----------
static __device__ __forceinline__ unsigned short f2bf(float f) {
    union { float f; unsigned int u; } cv; cv.f = f;
    unsigned int u = cv.u;
    unsigned int r = u + 0x7FFFu + ((u >> 16) & 1u);   // round-to-nearest-even
    return (unsigned short)(r >> 16);
}
static __device__ __forceinline__ unsigned int pack2(unsigned short a, unsigned short b) {
    return (unsigned int)a | ((unsigned int)b << 16);
}

// pack 2x float4 -> short8 (bf16) via v_cvt_pk_bf16_f32
#define PK8(d, fa, fb)                                                              \
    {                                                                               \
        __hip_bfloat162 p0_ = __float22bfloat162_rn(make_float2((fa).x, (fa).y));   \
        __hip_bfloat162 p1_ = __float22bfloat162_rn(make_float2((fa).z, (fa).w));   \
        __hip_bfloat162 p2_ = __float22bfloat162_rn(make_float2((fb).x, (fb).y));   \
        __hip_bfloat162 p3_ = __float22bfloat162_rn(make_float2((fb).z, (fb).w));   \
        union { uint4 u; short8 s; } cv_;                                           \
        cv_.u = make_uint4(*(unsigned int*)&p0_, *(unsigned int*)&p1_,              \
                           *(unsigned int*)&p2_, *(unsigned int*)&p3_);             \
        (d) = cv_.s;                                                                \
    }

// ---------- kernel 1: Wt fp32 -> bf16 (plain row-major, v7 layout) ----------
__global__ void cvt_wt_kernel(const float* __restrict__ wt, unsigned short* __restrict__ out) {
    int t = blockIdx.x * blockDim.x + threadIdx.x;     // 16384 threads
    const float4* p = (const float4*)wt;
    float4 f0 = p[t * 2], f1 = p[t * 2 + 1];
    uint4 v;
    v.x = pack2(f2bf(f0.x), f2bf(f0.y));
    v.y = pack2(f2bf(f0.z), f2bf(f0.w));
    v.z = pack2(f2bf(f1.x), f2bf(f1.y));
    v.w = pack2(f2bf(f1.z), f2bf(f1.w));
    ((uint4*)out)[t] = v;
}

// ---------- kernel 2: batch (int64 OR int32) -> int32 ----------
__global__ void cvt_batch_kernel(const void* __restrict__ batch, int* __restrict__ out, int n) {
    const long long* p64 = (const long long*)batch;
    const int* p32 = (const int*)batch;
    bool is64 = ((unsigned long long)p64[n / 2 - 1]) < (1ull << 20);
    for (int i = blockIdx.x * blockDim.x + threadIdx.x; i < n; i += gridDim.x * blockDim.x)
        out[i] = is64 ? (int)p64[i] : p32[i];
}

// ---------- kernel 3: gate logits (v9: persistent blocks, paced A-prefetch) ----------
// 512 persistent blocks; block processes tiles t, t+512, ... While computing
// tile t's 16 Wt-chunks, it paces 2 HBM x-loads/chunk for tile t+1 into a 2nd
// register set (a/a2 alternate via 2-body loop -- all static indexing).
// Keeps HBM continuously busy instead of front-loaded A-phase bursts.
// Wt: v7's verified path (3 rotating 16KB LDS bufs, global_load_lds,
// inverse-swizzled source + swizzled ds_read, counted vmcnt).
__global__ __launch_bounds__(256, 2) void gate_kernel(
    const float* __restrict__ x, const unsigned short* __restrict__ wtb,
    const float* __restrict__ bt, const float* __restrict__ wg,
    const float* __restrict__ bg, float* __restrict__ logits, int n)
{
    __shared__ __align__(16) char lds[53248];   // 3x16KB Wt bufs + 2KB bt + 2KB wg
    const int tid = threadIdx.x;
    const int lane = tid & 63;
    const int wid = tid >> 6;
    const int l31 = lane & 31;
    const int g = lane >> 5;                    // k-half 0/1
    const long ntiles = ((long)n + 127) >> 7;
    long t = blockIdx.x;
    if (t >= ntiles) return;

    // ---- stage bt/wg -> LDS
    {
        float2 b2 = ((const float2*)bt)[tid];
        float2 w2 = ((const float2*)wg)[tid];
        *(float2*)(lds + 49152 + tid * 8) = b2;
        *(float2*)(lds + 51200 + tid * 8) = w2;
    }
    const float bgv = bg[0];

    // per-lane Wt source offsets: physical granule p holds logical (rc, (p&31)^rc)
    int soff[4];
#pragma unroll
    for (int i = 0; i < 4; ++i) {
        int p = (wid * 4 + i) * 64 + lane;
        int rc = p >> 5;
        int gcl = (p & 31) ^ (rc & 31);
        soff[i] = rc * 512 + gcl * 16;
    }
    const char* wtbb = (const char*)wtb;

#define STAGE(c, bufoff)                                                              \
    {                                                                                 \
        const char* src_ = wtbb + (c) * 16384;                                        \
        char* dst_ = lds + (bufoff) + wid * 4096;                                     \
        _Pragma("unroll")                                                             \
        for (int i = 0; i < 4; ++i)                                                   \
            __builtin_amdgcn_global_load_lds(                                         \
                (const __attribute__((address_space(1))) unsigned int*)(src_ + soff[i]), \
                (__attribute__((address_space(3))) unsigned int*)(dst_ + i * 1024),   \
                16, 0, 0);                                                            \
    }

    // ---- burst-load A for first tile (once per block)
    short8 a[16], a2[16];
    {
        const long row = t * 128 + wid * 32 + l31;
        const bool ok = row < (long)n;
        const float4* xr = (const float4*)(x + (ok ? row : 0) * 256) + g * 2;
#pragma unroll
        for (int kt = 0; kt < 16; ++kt) {
            float4 q0 = ok ? xr[kt * 4]     : make_float4(0.f, 0.f, 0.f, 0.f);
            float4 q1 = ok ? xr[kt * 4 + 1] : make_float4(0.f, 0.f, 0.f, 0.f);
            PK8(a[kt], q0, q1)
        }
    }
    float4 f0p, f1p;
    __syncthreads();    // bt/wg visible; all vmem drained (A consumed)

    // one chunk iteration; W = end-of-iter vmcnt (4 normally, 0 for c>=14)
#define ITER(c, W, CUR, NXT)                                                          \
    {                                                                                 \
        __builtin_amdgcn_s_barrier();                                                 \
        if (nxtv) {                                                                   \
            f0p = okn ? xrn[(c) * 4]     : make_float4(0.f, 0.f, 0.f, 0.f);           \
            f1p = okn ? xrn[(c) * 4 + 1] : make_float4(0.f, 0.f, 0.f, 0.f);           \
        }                                                                             \
        __builtin_amdgcn_sched_barrier(0);                                            \
        if ((c) < 14) STAGE((c) + 2, (((c) + 2) % 3) * 16384)                         \
        {                                                                             \
            const char* bb = lds + ((c) % 3) * 16384 + l31 * 512;                     \
            f32x16 acc;                                                               \
            _Pragma("unroll")                                                         \
            for (int r = 0; r < 16; ++r) acc[r] = 0.f;                                \
            _Pragma("unroll")                                                         \
            for (int kt = 0; kt < 16; ++kt) {                                         \
                short8 b = *(const short8*)(bb + (((kt * 2 + g) ^ l31) * 16));        \
                acc = __builtin_amdgcn_mfma_f32_32x32x16_bf16(CUR[kt], b, acc, 0, 0, 0); \
            }                                                                         \
            const float btv = *(const float*)(lds + 49152 + ((c) * 32 + l31) * 4);    \
            const float wgv = *(const float*)(lds + 51200 + ((c) * 32 + l31) * 4);    \
            _Pragma("unroll")                                                         \
            for (int r = 0; r < 16; ++r) {                                            \
                float v = acc[r] + btv;                                               \
                float sp = fmaxf(v, 0.f) + __logf(1.f + __expf(-fabsf(v)));           \
                lp[r] = fmaf(sp, wgv, lp[r]);                                         \
            }                                                                         \
        }                                                                             \
        if (nxtv) PK8(NXT[(c)], f0p, f1p)                                             \
        asm volatile("s_waitcnt vmcnt(" #W ")" ::: "memory");                         \
    }

#define TILE_BODY(CUR, NXT, TCUR, TNXT)                                               \
    {                                                                                 \
        const long rowb = (TCUR) * 128L;                                              \
        const bool nxtv = (TNXT) < ntiles;                                            \
        const long rown_ = (TNXT) * 128L + wid * 32 + l31;                            \
        const bool okn = nxtv && (rown_ < (long)n);                                   \
        const float4* xrn = (const float4*)(x + (okn ? rown_ : 0) * 256) + g * 2;     \
        float lp[16];                                                                 \
        _Pragma("unroll")                                                             \
        for (int r = 0; r < 16; ++r) lp[r] = 0.f;                                     \
        __builtin_amdgcn_s_barrier();    /* prev tile's buf0 reads done (all waves)*/ \
        STAGE(0, 0) STAGE(1, 16384)                                                   \
        asm volatile("s_waitcnt vmcnt(4)" ::: "memory");                              \
        ITER(0, 4, CUR, NXT)  ITER(1, 4, CUR, NXT)  ITER(2, 4, CUR, NXT)              \
        ITER(3, 4, CUR, NXT)  ITER(4, 4, CUR, NXT)  ITER(5, 4, CUR, NXT)              \
        ITER(6, 4, CUR, NXT)  ITER(7, 4, CUR, NXT)  ITER(8, 4, CUR, NXT)              \
        ITER(9, 4, CUR, NXT)  ITER(10, 4, CUR, NXT) ITER(11, 4, CUR, NXT)             \
        ITER(12, 4, CUR, NXT) ITER(13, 4, CUR, NXT) ITER(14, 0, CUR, NXT)             \
        ITER(15, 0, CUR, NXT)                                                         \
        _Pragma("unroll")                                                             \
        for (int r = 0; r < 16; ++r) {                                                \
            float v = lp[r];                                                          \
            v += __shfl_xor(v, 1);  v += __shfl_xor(v, 2);                            \
            v += __shfl_xor(v, 4);  v += __shfl_xor(v, 8);                            \
            v += __shfl_xor(v, 16);                                                   \
            lp[r] = v;                                                                \
        }                                                                             \
        if (l31 == 0) {                                                               \
            _Pragma("unroll")                                                         \
            for (int r = 0; r < 16; ++r) {                                            \
                long row = rowb + wid * 32 + 4 * g + (r & 3) + 8 * (r >> 2);          \
                if (row < (long)n) logits[row] = lp[r] + bgv;                         \
            }                                                                         \
        }                                                                             \
    }

    while (true) {
        long tn = t + GATE_GRID;
        TILE_BODY(a, a2, t, tn)
        if (tn >= ntiles) break;
        t = tn; tn = t + GATE_GRID;
        TILE_BODY(a2, a, t, tn)
        if (tn >= ntiles) break;
        t = tn;
    }
#undef TILE_BODY
#undef ITER
#undef STAGE
}

// ---------- kernel 4: per-segment stats ----------
static __device__ __forceinline__ int lower_bound(const int* __restrict__ a, int n, int v) {
    int lo = 0, hi = n;
    while (lo < hi) { int mid = (lo + hi) >> 1; if (a[mid] < v) lo = mid + 1; else hi = mid; }
    return lo;
}

__global__ void segstats_kernel(const int* __restrict__ batch, const float* __restrict__ logits,
    float* __restrict__ segmax, float* __restrict__ segrs, float* __restrict__ seginv,
    int* __restrict__ segstart, int* __restrict__ segcnt, int n)
{
    const int b = blockIdx.x;
    __shared__ int sh_se[2];
    __shared__ float sh_red[4];
    const int tid = threadIdx.x;
    if (tid == 0) {
        sh_se[0] = lower_bound(batch, n, b);
        sh_se[1] = lower_bound(batch, n, b + 1);
    }
    __syncthreads();
    const int start = sh_se[0], end = sh_se[1];
    float m = -3.4e38f;
    for (int i = start + tid; i < end; i += 256) m = fmaxf(m, logits[i]);
#pragma unroll
    for (int mk = 1; mk <= 32; mk <<= 1) m = fmaxf(m, __shfl_xor(m, mk));
    if ((tid & 63) == 0) sh_red[tid >> 6] = m;
    __syncthreads();
    m = fmaxf(fmaxf(sh_red[0], sh_red[1]), fmaxf(sh_red[2], sh_red[3]));
    float s = 0.f;
    for (int i = start + tid; i < end; i += 256) s += __expf(logits[i] - m);
#pragma unroll
    for (int mk = 1; mk <= 32; mk <<= 1) s += __shfl_xor(s, mk);
    __syncthreads();
    if ((tid & 63) == 0) sh_red[tid >> 6] = s;
    __syncthreads();
    if (tid == 0) {
        s = sh_red[0] + sh_red[1] + sh_red[2] + sh_red[3];
        const int cnt = end - start;
        segmax[b] = m;
        segrs[b] = (s > 0.f) ? (1.f / s) : 0.f;
        seginv[b] = 1.f / (float)((cnt > 0) ? cnt : 1);
        segstart[b] = start;
        segcnt[b] = cnt;
    }
}

// ---------- kernel 5: pooled output, weights computed inline via LDS stage ----------
__global__ __launch_bounds__(256) void pool_kernel(const float* __restrict__ x,
    const float* __restrict__ logits, const float* __restrict__ segmax,
    const float* __restrict__ segrs, const float* __restrict__ seginv,
    const int* __restrict__ segstart, const int* __restrict__ segcnt,
    float* __restrict__ out)
{
    __shared__ float wsh[1024];
    const int b = blockIdx.x;
    const int c = threadIdx.x;
    const int start = segstart[b];
    const int cnt = segcnt[b];
    const float smax = segmax[b], srs = segrs[b], sinv = seginv[b];
    float acc = 0.f;
    for (int base = 0; base < cnt; base += 1024) {
        const int m = min(cnt - base, 1024);
        __syncthreads();
        for (int i = c; i < m; i += 256)
            wsh[i] = __expf(logits[start + base + i] - smax) * srs + sinv;
        __syncthreads();
        const float* xp = x + (size_t)(start + base) * CD + c;
        int i = 0;
        for (; i + 8 <= m; i += 8) {
            float x0 = xp[(size_t)(i+0)*CD], x1 = xp[(size_t)(i+1)*CD];
            float x2 = xp[(size_t)(i+2)*CD], x3 = xp[(size_t)(i+3)*CD];
            float x4 = xp[(size_t)(i+4)*CD], x5 = xp[(size_t)(i+5)*CD];
            float x6 = xp[(size_t)(i+6)*CD], x7 = xp[(size_t)(i+7)*CD];
            acc = fmaf(wsh[i+0],x0,fmaf(wsh[i+1],x1,fmaf(wsh[i+2],x2,fmaf(wsh[i+3],x3,acc))));
            acc = fmaf(wsh[i+4],x4,fmaf(wsh[i+5],x5,fmaf(wsh[i+6],x6,fmaf(wsh[i+7],x7,acc))));
        }
        for (; i < m; ++i) acc = fmaf(wsh[i], xp[(size_t)i*CD], acc);
    }
    out[(size_t)b * CD + c] = acc;
}

// ---------- launcher ----------
extern "C" void kernel_launch(void* const* d_in, const int* in_sizes, int n_in,
                              void* d_out, int out_size, void* d_ws, size_t ws_size,
                              hipStream_t stream)
{
    const float* x  = (const float*)d_in[0];
    const void*  batch = d_in[1];
    const float* Wt = (const float*)d_in[3];
    const float* bt = (const float*)d_in[4];
    const float* Wg = (const float*)d_in[5];
    const float* bg = (const float*)d_in[6];
    float* out = (float*)d_out;
    const int n = in_sizes[1];            // 400000
    const int nseg = out_size / CD;       // 1024

    char* ws = (char*)d_ws;
    size_t off = 0;
    unsigned short* wtb = (unsigned short*)(ws + off); off += (size_t)HD * CD * 2;
    float* logits = (float*)(ws + off); off += (size_t)n * 4;
    float* segmax = (float*)(ws + off); off += (size_t)nseg * 4;
    float* segrs  = (float*)(ws + off); off += (size_t)nseg * 4;
    float* seginv = (float*)(ws + off); off += (size_t)nseg * 4;
    int* segstart = (int*)(ws + off);   off += (size_t)nseg * 4;
    int* segcnt   = (int*)(ws + off);   off += (size_t)nseg * 4;
    int* batch32  = (int*)(ws + off);   off += (size_t)n * 4;

    int ntiles = (n + 127) / 128;
    int gblocks = ntiles < GATE_GRID ? ntiles : GATE_GRID;

    hipLaunchKernelGGL(cvt_wt_kernel, dim3((HD * CD / 8) / 256), dim3(256), 0, stream, Wt, wtb);
    hipLaunchKernelGGL(cvt_batch_kernel, dim3(512), dim3(256), 0, stream, batch, batch32, n);
    hipLaunchKernelGGL(gate_kernel, dim3(gblocks), dim3(256), 0, stream,
                       x, wtb, bt, Wg, bg, logits, n);
    hipLaunchKernelGGL(segstats_kernel, dim3(nseg), dim3(256), 0, stream,
                       batch32, logits, segmax, segrs, seginv, segstart, segcnt, n);
    hipLaunchKernelGGL(pool_kernel, dim3(nseg), dim3(256), 0, stream,
                       x, logits, segmax, segrs, seginv, segstart, segcnt, out);
}

// Round 11
// 299.081 us; speedup vs baseline: 4.4346x; 4.4346x over previous
//
#include <hip/hip_runtime.h>
#include <hip/hip_bf16.h>
#include <stdint.h>

typedef __attribute__((ext_vector_type(8))) short short8;
typedef __attribute__((ext_vector_type(16))) float f32x16;

#define CD 256   // channels
#define HD 512   // hidden

// ---------- helpers ----------
static __device__ __forceinline__ unsigned short f2bf(float f) {
    union { float f; unsigned int u; } cv; cv.f = f;
    unsigned int u = cv.u;
    unsigned int r = u + 0x7FFFu + ((u >> 16) & 1u);   // round-to-nearest-even
    return (unsigned short)(r >> 16);
}
static __device__ __forceinline__ unsigned int pack2(unsigned short a, unsigned short b) {
    return (unsigned int)a | ((unsigned int)b << 16);
}

// ---------- kernel 1: Wt fp32 -> bf16 ----------
__global__ void cvt_wt_kernel(const float* __restrict__ wt, unsigned short* __restrict__ out) {
    int t = blockIdx.x * blockDim.x + threadIdx.x;     // 16384 threads
    const float4* p = (const float4*)wt;
    float4 f0 = p[t * 2], f1 = p[t * 2 + 1];
    uint4 v;
    v.x = pack2(f2bf(f0.x), f2bf(f0.y));
    v.y = pack2(f2bf(f0.z), f2bf(f0.w));
    v.z = pack2(f2bf(f1.x), f2bf(f1.y));
    v.w = pack2(f2bf(f1.z), f2bf(f1.w));
    ((uint4*)out)[t] = v;
}

// ---------- kernel 2: batch (int64 OR int32) -> int32 ----------
__global__ void cvt_batch_kernel(const void* __restrict__ batch, int* __restrict__ out, int n) {
    const long long* p64 = (const long long*)batch;
    const int* p32 = (const int*)batch;
    bool is64 = ((unsigned long long)p64[n / 2 - 1]) < (1ull << 20);
    for (int i = blockIdx.x * blockDim.x + threadIdx.x; i < n; i += gridDim.x * blockDim.x)
        out[i] = is64 ? (int)p64[i] : p32[i];
}

// ---------- kernel 3: gate logits (v10b = v7 + dual independent MFMA chains) ----------
// 128 rows/block, 4 waves x 32 rows. A-frags direct from global (bf16 in-reg cvt).
// Wt: 16 chunks of 32 h (16KB), 3 rotating LDS buffers, prefetch depth 2,
// rolled loop + raw s_barrier + counted vmcnt(4) (R7's proven spill-free shell).
// NEW: per chunk, K=256 split into TWO independent 8-MFMA chains (acc0/acc1)
// to break the 16-deep accumulator dependency chain; merged in epilogue.
__global__ __launch_bounds__(256, 3) void gate_kernel(
    const float* __restrict__ x, const unsigned short* __restrict__ wtb,
    const float* __restrict__ bt, const float* __restrict__ wg,
    const float* __restrict__ bg, float* __restrict__ logits, int n)
{
    __shared__ __align__(16) char lds[53248];   // 48KB Wt bufs + 2KB bt + 2KB wg
    const int tid = threadIdx.x;
    const int lane = tid & 63;
    const int wid = tid >> 6;
    const int l31 = lane & 31;
    const int g = lane >> 5;                    // k-half 0/1
    const long rowbase = (long)blockIdx.x * 128;

    // ---- stage bt/wg -> LDS (one float2 per thread per array)
    {
        float2 b2 = ((const float2*)bt)[tid];
        float2 w2 = ((const float2*)wg)[tid];
        *(float2*)(lds + 49152 + tid * 8) = b2;
        *(float2*)(lds + 51200 + tid * 8) = w2;
    }

    // ---- A fragments: direct global loads, cvt in-reg
    short8 a[16];
    {
        const long row = rowbase + wid * 32 + l31;
        const bool ok = row < (long)n;
        const float4* xr = (const float4*)(x + row * 256) + g * 2;
#pragma unroll
        for (int kt = 0; kt < 16; ++kt) {
            float4 f0 = ok ? xr[kt * 4]     : make_float4(0.f, 0.f, 0.f, 0.f);
            float4 f1 = ok ? xr[kt * 4 + 1] : make_float4(0.f, 0.f, 0.f, 0.f);
            __hip_bfloat162 p0 = __float22bfloat162_rn(make_float2(f0.x, f0.y));
            __hip_bfloat162 p1 = __float22bfloat162_rn(make_float2(f0.z, f0.w));
            __hip_bfloat162 p2 = __float22bfloat162_rn(make_float2(f1.x, f1.y));
            __hip_bfloat162 p3 = __float22bfloat162_rn(make_float2(f1.z, f1.w));
            union { uint4 u; short8 s; } cv;
            cv.u = make_uint4(*(unsigned int*)&p0, *(unsigned int*)&p1,
                              *(unsigned int*)&p2, *(unsigned int*)&p3);
            a[kt] = cv.s;
        }
    }

    // per-lane Wt source offsets: physical granule p holds logical (rc, (p&31)^rc)
    int soff[4];
#pragma unroll
    for (int i = 0; i < 4; ++i) {
        int p = (wid * 4 + i) * 64 + lane;
        int rc = p >> 5;
        int gcl = (p & 31) ^ (rc & 31);
        soff[i] = rc * 512 + gcl * 16;
    }
    const char* wtbb = (const char*)wtb;

#define STAGE(c, bufoff)                                                              \
    {                                                                                 \
        const char* src = wtbb + (c) * 16384;                                         \
        char* dst = lds + (bufoff) + wid * 4096;                                      \
        _Pragma("unroll")                                                             \
        for (int i = 0; i < 4; ++i)                                                   \
            __builtin_amdgcn_global_load_lds(                                         \
                (const __attribute__((address_space(1))) unsigned int*)(src + soff[i]), \
                (__attribute__((address_space(3))) unsigned int*)(dst + i * 1024),    \
                16, 0, 0);                                                            \
    }

    // one chunk: two interleaved 8-MFMA chains, merged in the epilogue
#define COMPUTE(c)                                                                    \
    {                                                                                 \
        const char* bb = lds + ((c) % 3) * 16384 + l31 * 512;                         \
        f32x16 acc0, acc1;                                                            \
        _Pragma("unroll")                                                             \
        for (int r = 0; r < 16; ++r) { acc0[r] = 0.f; acc1[r] = 0.f; }                \
        _Pragma("unroll")                                                             \
        for (int kt = 0; kt < 8; ++kt) {                                              \
            short8 b0 = *(const short8*)(bb + (((kt * 2 + g) ^ l31) * 16));           \
            short8 b1 = *(const short8*)(bb + ((((kt + 8) * 2 + g) ^ l31) * 16));     \
            acc0 = __builtin_amdgcn_mfma_f32_32x32x16_bf16(a[kt], b0, acc0, 0, 0, 0); \
            acc1 = __builtin_amdgcn_mfma_f32_32x32x16_bf16(a[kt + 8], b1, acc1, 0, 0, 0); \
        }                                                                             \
        const float btv = *(const float*)(lds + 49152 + ((c) * 32 + l31) * 4);        \
        const float wgv = *(const float*)(lds + 51200 + ((c) * 32 + l31) * 4);        \
        _Pragma("unroll")                                                             \
        for (int r = 0; r < 16; ++r) {                                                \
            float v = acc0[r] + acc1[r] + btv;                                        \
            float sp = fmaxf(v, 0.f) + __logf(1.f + __expf(-__builtin_fabsf(v)));     \
            lp[r] = fmaf(sp, wgv, lp[r]);                                             \
        }                                                                             \
    }

    float lp[16];
#pragma unroll
    for (int r = 0; r < 16; ++r) lp[r] = 0.f;

    __syncthreads();            // bt/wg visible; all prior vmem drained (A consumed)

    STAGE(0, 0);
    STAGE(1, 16384);

#pragma unroll 1
    for (int c = 0; c < 15; ++c) {
        // outstanding here = stage(c) + stage(c+1) = 8 loads; retire stage(c) only.
        asm volatile("s_waitcnt vmcnt(4)" ::: "memory");
        __builtin_amdgcn_s_barrier();
        if (c < 14) STAGE(c + 2, ((c + 2) % 3) * 16384);
        COMPUTE(c);
    }
    // peeled last chunk: only stage(15) outstanding
    asm volatile("s_waitcnt vmcnt(0)" ::: "memory");
    __builtin_amdgcn_s_barrier();
    COMPUTE(15);
#undef COMPUTE
#undef STAGE

    // reduce over the 32 h-lanes within each half, write logits
#pragma unroll
    for (int r = 0; r < 16; ++r) {
        float v = lp[r];
        v += __shfl_xor(v, 1);
        v += __shfl_xor(v, 2);
        v += __shfl_xor(v, 4);
        v += __shfl_xor(v, 8);
        v += __shfl_xor(v, 16);
        lp[r] = v;
    }
    if (l31 == 0) {
        const float bgv = bg[0];
#pragma unroll
        for (int r = 0; r < 16; ++r) {
            long row = rowbase + wid * 32 + 4 * g + (r & 3) + 8 * (r >> 2);  // C/D layout (m74/m101)
            if (row < (long)n) logits[row] = lp[r] + bgv;
        }
    }
}

// ---------- kernel 4: per-segment stats ----------
static __device__ __forceinline__ int lower_bound(const int* __restrict__ a, int n, int v) {
    int lo = 0, hi = n;
    while (lo < hi) { int mid = (lo + hi) >> 1; if (a[mid] < v) lo = mid + 1; else hi = mid; }
    return lo;
}

__global__ void segstats_kernel(const int* __restrict__ batch, const float* __restrict__ logits,
    float* __restrict__ segmax, float* __restrict__ segrs, float* __restrict__ seginv,
    int* __restrict__ segstart, int* __restrict__ segcnt, int n)
{
    const int b = blockIdx.x;
    __shared__ int sh_se[2];
    __shared__ float sh_red[4];
    const int tid = threadIdx.x;
    if (tid == 0) {
        sh_se[0] = lower_bound(batch, n, b);
        sh_se[1] = lower_bound(batch, n, b + 1);
    }
    __syncthreads();
    const int start = sh_se[0], end = sh_se[1];
    float m = -3.4e38f;
    for (int i = start + tid; i < end; i += 256) m = fmaxf(m, logits[i]);
#pragma unroll
    for (int mk = 1; mk <= 32; mk <<= 1) m = fmaxf(m, __shfl_xor(m, mk));
    if ((tid & 63) == 0) sh_red[tid >> 6] = m;
    __syncthreads();
    m = fmaxf(fmaxf(sh_red[0], sh_red[1]), fmaxf(sh_red[2], sh_red[3]));
    float s = 0.f;
    for (int i = start + tid; i < end; i += 256) s += __expf(logits[i] - m);
#pragma unroll
    for (int mk = 1; mk <= 32; mk <<= 1) s += __shfl_xor(s, mk);
    __syncthreads();
    if ((tid & 63) == 0) sh_red[tid >> 6] = s;
    __syncthreads();
    if (tid == 0) {
        s = sh_red[0] + sh_red[1] + sh_red[2] + sh_red[3];
        const int cnt = end - start;
        segmax[b] = m;
        segrs[b] = (s > 0.f) ? (1.f / s) : 0.f;
        seginv[b] = 1.f / (float)((cnt > 0) ? cnt : 1);
        segstart[b] = start;
        segcnt[b] = cnt;
    }
}

// ---------- kernel 5: pooled output, weights computed inline via LDS stage ----------
// out[b,c] = sum_i (exp(logit_i - smax)*srs + 1/cnt) * x[i,c]
__global__ __launch_bounds__(256) void pool_kernel(const float* __restrict__ x,
    const float* __restrict__ logits, const float* __restrict__ segmax,
    const float* __restrict__ segrs, const float* __restrict__ seginv,
    const int* __restrict__ segstart, const int* __restrict__ segcnt,
    float* __restrict__ out)
{
    __shared__ float wsh[1024];
    const int b = blockIdx.x;
    const int c = threadIdx.x;
    const int start = segstart[b];
    const int cnt = segcnt[b];
    const float smax = segmax[b], srs = segrs[b], sinv = seginv[b];
    float acc = 0.f;
    for (int base = 0; base < cnt; base += 1024) {
        const int m = min(cnt - base, 1024);
        __syncthreads();
        for (int i = c; i < m; i += 256)
            wsh[i] = __expf(logits[start + base + i] - smax) * srs + sinv;
        __syncthreads();
        const float* xp = x + (size_t)(start + base) * CD + c;
        int i = 0;
        for (; i + 8 <= m; i += 8) {
            float x0 = xp[(size_t)(i+0)*CD], x1 = xp[(size_t)(i+1)*CD];
            float x2 = xp[(size_t)(i+2)*CD], x3 = xp[(size_t)(i+3)*CD];
            float x4 = xp[(size_t)(i+4)*CD], x5 = xp[(size_t)(i+5)*CD];
            float x6 = xp[(size_t)(i+6)*CD], x7 = xp[(size_t)(i+7)*CD];
            acc = fmaf(wsh[i+0],x0,fmaf(wsh[i+1],x1,fmaf(wsh[i+2],x2,fmaf(wsh[i+3],x3,acc))));
            acc = fmaf(wsh[i+4],x4,fmaf(wsh[i+5],x5,fmaf(wsh[i+6],x6,fmaf(wsh[i+7],x7,acc))));
        }
        for (; i < m; ++i) acc = fmaf(wsh[i], xp[(size_t)i*CD], acc);
    }
    out[(size_t)b * CD + c] = acc;
}

// ---------- launcher ----------
extern "C" void kernel_launch(void* const* d_in, const int* in_sizes, int n_in,
                              void* d_out, int out_size, void* d_ws, size_t ws_size,
                              hipStream_t stream)
{
    const float* x  = (const float*)d_in[0];
    const void*  batch = d_in[1];
    const float* Wt = (const float*)d_in[3];
    const float* bt = (const float*)d_in[4];
    const float* Wg = (const float*)d_in[5];
    const float* bg = (const float*)d_in[6];
    float* out = (float*)d_out;
    const int n = in_sizes[1];            // 400000
    const int nseg = out_size / CD;       // 1024

    char* ws = (char*)d_ws;
    size_t off = 0;
    unsigned short* wtb = (unsigned short*)(ws + off); off += (size_t)HD * CD * 2;
    float* logits = (float*)(ws + off); off += (size_t)n * 4;
    float* segmax = (float*)(ws + off); off += (size_t)nseg * 4;
    float* segrs  = (float*)(ws + off); off += (size_t)nseg * 4;
    float* seginv = (float*)(ws + off); off += (size_t)nseg * 4;
    int* segstart = (int*)(ws + off);   off += (size_t)nseg * 4;
    int* segcnt   = (int*)(ws + off);   off += (size_t)nseg * 4;
    int* batch32  = (int*)(ws + off);   off += (size_t)n * 4;

    hipLaunchKernelGGL(cvt_wt_kernel, dim3((HD * CD / 8) / 256), dim3(256), 0, stream, Wt, wtb);
    hipLaunchKernelGGL(cvt_batch_kernel, dim3(512), dim3(256), 0, stream, batch, batch32, n);
    hipLaunchKernelGGL(gate_kernel, dim3((n + 127) / 128), dim3(256), 0, stream,
                       x, wtb, bt, Wg, bg, logits, n);
    hipLaunchKernelGGL(segstats_kernel, dim3(nseg), dim3(256), 0, stream,
                       batch32, logits, segmax, segrs, seginv, segstart, segcnt, n);
    hipLaunchKernelGGL(pool_kernel, dim3(nseg), dim3(256), 0, stream,
                       x, logits, segmax, segrs, seginv, segstart, segcnt, out);
}